// Round 1
// 196.239 us; speedup vs baseline: 1.1684x; 1.1684x over previous
//
#include <hip/hip_runtime.h>
#include <cstdint>

// Problem constants (fixed by setup_inputs): B=4, N=16384, P=1024, C=128
#define BQ_B 4
#define BQ_N 16384
#define BQ_P 1024
#define BQ_C 128
#define NS   64
#define R2   0.04f

// Output layout (flat concat, fp32):
//   region 1: new_features (B,131,P,NS)
//   region 2: grouped_xyz  (B,3,P,NS)
//   region 3: idx0         (B,P,NS) stored as float
#define O1 ((size_t)BQ_B * 131 * BQ_P * NS)
#define O2 (O1 + (size_t)BQ_B * 3 * BQ_P * NS)

// ws layout: wsIdx (B*P, NS) int32 at offset 0 (1 MB). No transposed-features
// staging anymore — the gather kernel reads features (B,C,N) directly.

// ---------------- Kernel 1: ball query, one WAVE per center ----------------
// 4096 centers = 4096 waves (1024 blocks x 4 waves). No __syncthreads at all:
// each wave scans xyz in ascending order in chunks of 512 points (8x64),
// compacts hit indices via ballot/popc rank into its private LDS strip, and
// early-exits once 64 hits are found. Lane t == output slot t (NS == wave64).
__global__ __launch_bounds__(256) void ballquery_kernel(
    const float* __restrict__ xyz,      // (B, N, 3)
    const float* __restrict__ new_xyz,  // (B, P, 3)
    int* __restrict__ wsIdx,            // (B*P, NS) gather index (BQ_N = pad)
    float* __restrict__ out)
{
#pragma clang fp contract(off)   // match np reference exactly at the radius boundary
    const int lane = threadIdx.x & 63;
    const int w    = threadIdx.x >> 6;            // wave 0..3
    const int center = blockIdx.x * 4 + w;
    const int b = center >> 10;
    const int p = center & (BQ_P - 1);

    __shared__ int lidx[4][NS];                   // per-wave strip, no cross-wave use

    const float cx = new_xyz[center * 3 + 0];
    const float cy = new_xyz[center * 3 + 1];
    const float cz = new_xyz[center * 3 + 2];
    const float* xb = xyz + (size_t)b * BQ_N * 3;

    const unsigned long long lmask = (1ull << lane) - 1ull;
    int total = 0;

    for (int base = 0; base < BQ_N; base += 512) {
        float d2a[8];
        #pragma unroll
        for (int u = 0; u < 8; ++u) {             // 24 loads in flight (dwordx3/pt)
            const int i = base + u * 64 + lane;
            const float dx = xb[i * 3 + 0] - cx;
            const float dy = xb[i * 3 + 1] - cy;
            const float dz = xb[i * 3 + 2] - cz;
            d2a[u] = dx * dx + dy * dy + dz * dz;
        }
        #pragma unroll
        for (int u = 0; u < 8; ++u) {             // ascending rank assignment
            const unsigned long long m = __ballot(d2a[u] < R2);
            if ((m >> lane) & 1ull) {
                const int r = total + (int)__popcll(m & lmask);
                if (r < NS) lidx[w][r] = base + u * 64 + lane;
            }
            total += (int)__popcll(m);            // wave-uniform
        }
        if (total >= NS) break;                   // uniform branch
    }
    __threadfence_block();   // drain lgkm: same-wave LDS RAW before the reads below

    const int tt    = (total > NS) ? NS : total;
    const int first = (total > 0) ? lidx[w][0] : BQ_N;
    const int v     = (lane < tt) ? lidx[w][lane] : BQ_N;   // BQ_N = pad slot
    const int idx0  = (lane < tt) ? v : first;
    const bool real = v < BQ_N;

    wsIdx[(size_t)center * NS + lane] = v;
    out[O2 + (size_t)center * NS + lane] = (float)idx0;

    #pragma unroll
    for (int d = 0; d < 3; ++d) {
        const float c  = (d == 0) ? cx : ((d == 1) ? cy : cz);
        const float pt = real ? xb[v * 3 + d] : 1000000.0f;
        const float g  = pt - c;
        out[O1 + ((size_t)(b * 3 + d) * BQ_P + p) * NS + lane] = g;
        const float xf = ((g > 100000.0f) ? 0.0f : g) / 0.2f;
        out[((size_t)(b * 131 + d) * BQ_P + p) * NS + lane] = xf;
    }
}

// ---------------- Kernel 2: per-(b,c) channel-row gather ----------------
// One block per (batch, channel): stage features[b][c][0:N] (64 KB, the
// static-LDS max) once, then produce the entire (P,NS) output plane for that
// channel with coalesced int4 idx loads, LDS gathers, and float4 stores.
// Output layout (b, 3+c, p, s) is channel-major, so writes are a single
// contiguous 256 KB stream per block. No transpose ws round-trip.
__global__ __launch_bounds__(512) void feat_gather_kernel(
    const float* __restrict__ features, // (B, C, N)
    const int* __restrict__ wsIdx,      // (B*P, NS)
    float* __restrict__ out)
{
    const int b = blockIdx.x >> 7;
    const int c = blockIdx.x & 127;
    const int t = threadIdx.x;

    __shared__ float row[BQ_N];         // 65536 B: 2 blocks/CU (128 KB of 160 KB)

    const float4* fr = (const float4*)(features + ((size_t)b * BQ_C + c) * BQ_N);
    float4* row4 = (float4*)row;
    #pragma unroll
    for (int k = 0; k < 8; ++k)         // 512 thr x 8 x 16 B = 64 KB coalesced
        row4[k * 512 + t] = fr[k * 512 + t];
    __syncthreads();

    const int4* gi4 = (const int4*)(wsIdx + (size_t)b * BQ_P * NS);  // L2-hot
    float4* op = (float4*)(out + (size_t)(b * 131 + 3 + c) * BQ_P * NS);
    #pragma unroll 4
    for (int k = 0; k < 32; ++k) {      // 16384 quads / 512 threads
        const int q = k * 512 + t;
        const int4 gi = gi4[q];
        float4 v;
        v.x = (gi.x < BQ_N) ? row[gi.x] : 0.0f;   // pad slot -> 0 (feats_pad)
        v.y = (gi.y < BQ_N) ? row[gi.y] : 0.0f;
        v.z = (gi.z < BQ_N) ? row[gi.z] : 0.0f;
        v.w = (gi.w < BQ_N) ? row[gi.w] : 0.0f;
        op[q] = v;                       // 8 KB/wave-instr, contiguous stream
    }
}

extern "C" void kernel_launch(void* const* d_in, const int* in_sizes, int n_in,
                              void* d_out, int out_size, void* d_ws, size_t ws_size,
                              hipStream_t stream) {
    const float* xyz      = (const float*)d_in[0];  // (4,16384,3)
    const float* new_xyz  = (const float*)d_in[1];  // (4,1024,3)
    const float* features = (const float*)d_in[2];  // (4,128,16384)
    float* out = (float*)d_out;
    int*   wsIdx = (int*)d_ws;

    ballquery_kernel<<<dim3(BQ_B * BQ_P / 4), dim3(256), 0, stream>>>(xyz, new_xyz, wsIdx, out);
    feat_gather_kernel<<<dim3(BQ_B * BQ_C), dim3(512), 0, stream>>>(features, wsIdx, out);
}